// Round 2
// baseline (904.000 us; speedup 1.0000x reference)
//
#include <hip/hip_runtime.h>

#define THREADS 256
#define ROWS_PER_TILE 256
#define ROW 25
#define TILE_FLOATS (ROWS_PER_TILE * ROW)     // 6400
#define TILE_VEC4 (TILE_FLOATS / 4)           // 1600
#define PF_ITERS ((TILE_VEC4 + THREADS - 1) / THREADS)  // 7
#define NBLOCKS 768                            // 3 blocks/CU * 256 CUs, matches 50.5KB-LDS residency

// 3 waves/EU * 4 EU / 4 waves-per-block = 3 blocks/CU; caps VGPR ~168.
__global__ __launch_bounds__(THREADS, 3)
void loss_main_kernel(const float* __restrict__ pre, const float* __restrict__ tar,
                      float* __restrict__ partials, int B) {
    __shared__ float s_pre[TILE_FLOATS];
    __shared__ float s_tar[TILE_FLOATS];
    __shared__ float s_part[THREADS / 64];

    const int tid = threadIdx.x;
    const int ntiles = (B + ROWS_PER_TILE - 1) / ROWS_PER_TILE;   // 15625
    const long long total_vec4 = ((long long)B * ROW) / 4;        // 100M/4, exact

    const float4* gp = (const float4*)pre;
    const float4* gt = (const float4*)tar;

    float4 pf_p[PF_ITERS], pf_t[PF_ITERS];
    float acc = 0.0f;

    int tile = blockIdx.x;

    // Prefetch first tile into registers.
    if (tile < ntiles) {
        const long long vbase = (long long)tile * TILE_VEC4;
        #pragma unroll
        for (int k = 0; k < PF_ITERS; ++k) {
            int l = tid + k * THREADS;
            long long idx = vbase + l;
            if (l < TILE_VEC4 && idx < total_vec4) { pf_p[k] = gp[idx]; pf_t[k] = gt[idx]; }
        }
    }

    for (; tile < ntiles; tile += NBLOCKS) {
        // Drain prefetch into LDS.
        float4* sp = (float4*)s_pre;
        float4* st = (float4*)s_tar;
        #pragma unroll
        for (int k = 0; k < PF_ITERS; ++k) {
            int l = tid + k * THREADS;
            if (l < TILE_VEC4) { sp[l] = pf_p[k]; st[l] = pf_t[k]; }
        }
        __syncthreads();

        // Issue NEXT tile's global loads now — in flight during compute below.
        const int ntile = tile + NBLOCKS;
        if (ntile < ntiles) {
            const long long vbase = (long long)ntile * TILE_VEC4;
            #pragma unroll
            for (int k = 0; k < PF_ITERS; ++k) {
                int l = tid + k * THREADS;
                long long idx = vbase + l;
                if (l < TILE_VEC4 && idx < total_vec4) { pf_p[k] = gp[idx]; pf_t[k] = gt[idx]; }
            }
        }

        // Compute this tile from LDS (row stride 25 is odd -> 2 lanes/bank, conflict-free).
        const int row = tile * ROWS_PER_TILE + tid;
        if (row < B) {
            const float* rp = &s_pre[tid * ROW];
            const float* rt = &s_tar[tid * ROW];
            float total = 0.0f;
            #pragma unroll
            for (int c = 0; c < 6; ++c) {
                float x0 = rp[c * 4 + 0];
                float x1 = rp[c * 4 + 1];
                float x2 = rp[c * 4 + 2];
                float x3 = rp[c * 4 + 3];
                float m = fmaxf(fmaxf(x0, x1), fmaxf(x2, x3));
                float e0 = __expf(x0 - m);
                float e1 = __expf(x1 - m);
                float e2 = __expf(x2 - m);
                float e3 = __expf(x3 - m);
                float kk = 3.0f / (e0 + e1 + e2 + e3);
                total += fabsf(e0 * kk - rt[c * 4 + 0]);
                total += fabsf(e1 * kk - rt[c * 4 + 1]);
                total += fabsf(e2 * kk - rt[c * 4 + 2]);
                total += fabsf(e3 * kk - rt[c * 4 + 3]);
            }
            acc += total * (1.0f / 24.0f);
        }
        __syncthreads();   // protect LDS before next overwrite
    }

    // Block reduction: wave shuffle -> LDS -> one partial per block (no atomics).
    #pragma unroll
    for (int off = 32; off > 0; off >>= 1)
        acc += __shfl_down(acc, off, 64);
    if ((tid & 63) == 0) s_part[tid >> 6] = acc;
    __syncthreads();
    if (tid == 0)
        partials[blockIdx.x] = s_part[0] + s_part[1] + s_part[2] + s_part[3];
}

__global__ __launch_bounds__(THREADS)
void loss_reduce_kernel(const float* __restrict__ partials, float* __restrict__ out, int n) {
    __shared__ float s_part[THREADS / 64];
    const int tid = threadIdx.x;
    float v = 0.0f;
    for (int i = tid; i < n; i += THREADS) v += partials[i];
    #pragma unroll
    for (int off = 32; off > 0; off >>= 1)
        v += __shfl_down(v, off, 64);
    if ((tid & 63) == 0) s_part[tid >> 6] = v;
    __syncthreads();
    if (tid == 0)
        out[0] = s_part[0] + s_part[1] + s_part[2] + s_part[3];
}

extern "C" void kernel_launch(void* const* d_in, const int* in_sizes, int n_in,
                              void* d_out, int out_size, void* d_ws, size_t ws_size,
                              hipStream_t stream) {
    const float* pre = (const float*)d_in[0];
    const float* tar = (const float*)d_in[1];
    float* out = (float*)d_out;
    float* partials = (float*)d_ws;            // NBLOCKS floats of scratch
    const int B = in_sizes[0] / ROW;           // 4,000,000

    loss_main_kernel<<<NBLOCKS, THREADS, 0, stream>>>(pre, tar, partials, B);
    loss_reduce_kernel<<<1, THREADS, 0, stream>>>(partials, out, NBLOCKS);
}